// Round 8
// baseline (1556.269 us; speedup 1.0000x reference)
//
#include <hip/hip_runtime.h>
#include <math.h>

// Problem constants
#define BB 4
#define CC 64
#define HH 64
#define WW 4096
#define TW 128
#define THREADS 512            // R7: 8 waves/block (was 4) -> 4 waves/SIMD
#define NT (WW / TW)            // 32 tiles along W
#define CH_STRIDE ((size_t)HH * WW)   // 262144

#if __has_builtin(__builtin_amdgcn_rcpf)
__device__ __forceinline__ float fast_rcp(float v) { return __builtin_amdgcn_rcpf(v); }
#else
__device__ __forceinline__ float fast_rcp(float v) { return 1.0f / v; }
#endif

// ---------------------------------------------------------------------------
// Prep kernel: reshuffle weights into vector-load-friendly layouts in d_ws.
// WA[gc][c][k][tap][fg]  : 16 * 32 * 16 = 8192 floats   (conv weights)
//   gc 0..7  -> left conv (wl), rows jr = (gc&7)*4 + k, f=row jr, g=row jr+32
//   gc 8..15 -> right conv (wr)
// WB[gc][c][j]           : 16 * 64 * 8 = 8192 floats    (pointwise weights)
//   gc 0..7  -> w_skp rows (gc&7)*8 + j ; gc 8..15 -> w_hid rows
// ---------------------------------------------------------------------------
__global__ void prep_weights(const float* __restrict__ wl, const float* __restrict__ wr,
                             const float* __restrict__ w_skp, const float* __restrict__ w_hid,
                             float* __restrict__ WA, float* __restrict__ WB) {
    int i = blockIdx.x * blockDim.x + threadIdx.x;
    if (i < 8192) {
        // WA decode: i = (((gc*32 + c)*4 + k)*2 + tap)*2 + fg
        int fg  = i & 1;
        int tap = (i >> 1) & 1;
        int k   = (i >> 2) & 3;
        int c   = (i >> 4) & 31;
        int gc  = i >> 9;
        int half = gc >> 3;
        int jr   = (gc & 7) * 4 + k;
        const float* wsrc = half ? wr : wl;     // [64][32][1][2] flat: o*64 + c*2 + t
        int o = jr + (fg ? 32 : 0);
        WA[i] = wsrc[o * 64 + c * 2 + tap];

        // WB decode: i = (gc*64 + c)*8 + j
        int j  = i & 7;
        int c2 = (i >> 3) & 63;
        int g2 = i >> 9;
        int is_hid = g2 >> 3;
        int r = (g2 & 7) * 8 + j;
        const float* psrc = is_hid ? w_hid : w_skp;  // [64][64] flat: o*64 + c
        WB[i] = psrc[r * 64 + c2];
    }
}

// ---------------------------------------------------------------------------
// Fused residual-block kernel.
// Block = one (b, h, w-tile). 512 threads = 8 waves; each wave owns 2 gc.
// Lane -> 2 consecutive w positions (w0 = lane*2).
//
// History: R4 baseline (SMEM weights) 1102us, VALUBusy 26%. R7 (VMEM weights)
// 1122us, VALUBusy 31%, VGPR 124 -> latency-bound at 2 waves/SIMD, not a
// counter-mixing problem. R8: same tile/work, 8 waves/block -> 16 waves/CU
// (4/SIMD) to hide VMEM/LDS latency via TLP. VGPR cap 128 (was using 124).
// ---------------------------------------------------------------------------
__global__ __launch_bounds__(THREADS, 4)
void resblock_kernel(const float* __restrict__ x,
                     const float* __restrict__ WA, const float* __restrict__ WB,
                     const float* __restrict__ bl, const float* __restrict__ br,
                     const float* __restrict__ b_skp, const float* __restrict__ b_hid,
                     float* __restrict__ out1, float* __restrict__ out2) {
    __shared__ float Xs[CC][TW + 8];   // cols: 0..3 left halo, 4..131 body, 132..135 right halo
    __shared__ float Hs[CC][TW];       // gated activations

    const int tid = threadIdx.x;
    const int bid = blockIdx.x;
    const int wt = bid & (NT - 1);
    const int h  = (bid >> 5) & (HH - 1);
    const int b  = bid >> 11;
    const int w_base = wt * TW;

    const float* xrow = x + ((size_t)b * CC) * CH_STRIDE + (size_t)h * WW; // x[b][0][h][0]

    // opaque zero in a VGPR: forces weight addresses into VGPRs -> VMEM loads
    int zoff = 0;
    asm volatile("" : "+v"(zoff));

    // ---- load x tile into LDS ----
    // body: 64 rows x 32 float4 (aligned, fully in-bounds)
    for (int i = tid; i < CC * 32; i += THREADS) {
        int row = i >> 5, c4 = i & 31;
        float4 v = *reinterpret_cast<const float4*>(xrow + (size_t)row * CH_STRIDE + w_base + c4 * 4);
        *reinterpret_cast<float4*>(&Xs[row][4 + c4 * 4]) = v;
    }
    // halos: 64 rows x 8 scalars, zero-padded at edges
    for (int i = tid; i < CC * 8; i += THREADS) {
        int row = i >> 3, k = i & 7;
        int col = (k < 4) ? k : (TW + k);          // 0..3 or 132..135
        int gw = w_base + col - 4;
        float v = 0.0f;
        if (gw >= 0 && gw < WW) v = xrow[(size_t)row * CH_STRIDE + gw];
        Xs[row][col] = v;
    }
    __syncthreads();

    const int wave = __builtin_amdgcn_readfirstlane(tid >> 6);   // 0..7
    const int lane = tid & 63;
    const int w0 = lane * 2;                       // tile-local position

    // ---- Stage A: dilated convs + gated activation -> Hs ----
    // wave handles gc = wave*2 + it (it = 0,1); each gc = 4 (f,g) pairs x 2 w.
    for (int it = 0; it < 2; ++it) {
        int gc = wave * 2 + it;
        int half = gc >> 3;                        // 0: left conv, 1: right conv (uniform per wave)
        int jr0 = (gc & 7) * 4;
        const float4* wa4 = reinterpret_cast<const float4*>(WA + gc * 512 + zoff); // VGPR address
        int xr0 = half * 32;                       // input channel base
        int xbase = w0 + (half ? 4 : 0);           // tap-0 LDS col for this lane
        const float* bsrc = half ? br : bl;

        float accf[4][2], accg[4][2];
        #pragma unroll
        for (int k = 0; k < 4; ++k) {
            float bf = bsrc[jr0 + k];
            float bg = bsrc[jr0 + k + 32];
            accf[k][0] = bf; accf[k][1] = bf;
            accg[k][0] = bg; accg[k][1] = bg;
        }

        #pragma unroll 8
        for (int c = 0; c < 32; ++c) {
            float x0 = Xs[xr0 + c][xbase];         // tap0 @ w0
            float x1 = Xs[xr0 + c][xbase + 1];     // tap0 @ w0+1
            float x2 = Xs[xr0 + c][xbase + 4];     // tap1 @ w0
            float x3 = Xs[xr0 + c][xbase + 5];     // tap1 @ w0+1
            float4 wk[4];                          // wk[k] = (t0f, t0g, t1f, t1g)
            wk[0] = wa4[c * 4 + 0];
            wk[1] = wa4[c * 4 + 1];
            wk[2] = wa4[c * 4 + 2];
            wk[3] = wa4[c * 4 + 3];
            #pragma unroll
            for (int k = 0; k < 4; ++k) {
                accf[k][0] += wk[k].x * x0; accf[k][0] += wk[k].z * x2;
                accf[k][1] += wk[k].x * x1; accf[k][1] += wk[k].z * x3;
                accg[k][0] += wk[k].y * x0; accg[k][0] += wk[k].w * x2;
                accg[k][1] += wk[k].y * x1; accg[k][1] += wk[k].w * x3;
            }
        }

        // activation: h = tanh(f) * sigmoid(g)
        #pragma unroll
        for (int k = 0; k < 4; ++k) {
            int ch = half * 32 + jr0 + k;
            #pragma unroll
            for (int n = 0; n < 2; ++n) {
                float f = accf[k][n], g = accg[k][n];
                float th = 1.0f - 2.0f * fast_rcp(1.0f + __expf(2.0f * f));
                float sg = fast_rcp(1.0f + __expf(-g));
                Hs[ch][w0 + n] = th * sg;
            }
        }
    }
    __syncthreads();

    // ---- Stage B: two 64x64 pointwise matmuls + bias + residual ----
    for (int it = 0; it < 2; ++it) {
        int gc = wave * 2 + it;
        int is_hid = gc >> 3;                      // uniform per wave
        int r0 = (gc & 7) * 8;
        const float4* wb4 = reinterpret_cast<const float4*>(WB + gc * 512 + zoff); // VGPR address
        const float* bsrc = is_hid ? b_hid : b_skp;

        float acc[8][2];
        #pragma unroll
        for (int j = 0; j < 8; ++j) {
            float bv = bsrc[r0 + j];
            acc[j][0] = bv; acc[j][1] = bv;
        }

        #pragma unroll 8
        for (int c = 0; c < 64; ++c) {
            float h0 = Hs[c][w0];
            float h1 = Hs[c][w0 + 1];
            float4 wlo = wb4[c * 2 + 0];           // weights j=0..3
            float4 whi = wb4[c * 2 + 1];           // weights j=4..7
            acc[0][0] += wlo.x * h0; acc[0][1] += wlo.x * h1;
            acc[1][0] += wlo.y * h0; acc[1][1] += wlo.y * h1;
            acc[2][0] += wlo.z * h0; acc[2][1] += wlo.z * h1;
            acc[3][0] += wlo.w * h0; acc[3][1] += wlo.w * h1;
            acc[4][0] += whi.x * h0; acc[4][1] += whi.x * h1;
            acc[5][0] += whi.y * h0; acc[5][1] += whi.y * h1;
            acc[6][0] += whi.z * h0; acc[6][1] += whi.z * h1;
            acc[7][0] += whi.w * h0; acc[7][1] += whi.w * h1;
        }

        float* outp = is_hid ? out1 : out2;
        #pragma unroll
        for (int j = 0; j < 8; ++j) {
            int ch = r0 + j;
            float v0 = acc[j][0], v1 = acc[j][1];
            if (is_hid) {                          // residual: x + hid
                v0 += Xs[ch][w0 + 4];
                v1 += Xs[ch][w0 + 5];
            }
            size_t oidx = (((size_t)b * CC + ch) * HH + h) * WW + w_base + w0;
            float2 vv = make_float2(v0, v1);
            *reinterpret_cast<float2*>(outp + oidx) = vv;
        }
    }
}

// ---------------------------------------------------------------------------
extern "C" void kernel_launch(void* const* d_in, const int* in_sizes, int n_in,
                              void* d_out, int out_size, void* d_ws, size_t ws_size,
                              hipStream_t stream) {
    const float* x     = (const float*)d_in[0];
    const float* wl    = (const float*)d_in[1];
    const float* bl    = (const float*)d_in[2];
    const float* wr    = (const float*)d_in[3];
    const float* br    = (const float*)d_in[4];
    const float* w_skp = (const float*)d_in[5];
    const float* b_skp = (const float*)d_in[6];
    const float* w_hid = (const float*)d_in[7];
    const float* b_hid = (const float*)d_in[8];

    float* WA = (float*)d_ws;          // 8192 floats
    float* WB = WA + 8192;             // 8192 floats (total 64 KB of d_ws)

    float* out1 = (float*)d_out;                           // x + hid
    float* out2 = out1 + (size_t)BB * CC * HH * WW;        // o (skip)

    prep_weights<<<32, 256, 0, stream>>>(wl, wr, w_skp, w_hid, WA, WB);

    int grid = BB * HH * NT;   // 4*64*32 = 8192
    resblock_kernel<<<grid, THREADS, 0, stream>>>(x, WA, WB, bl, br, b_skp, b_hid, out1, out2);
}

// Round 10
// 1206.504 us; speedup vs baseline: 1.2899x; 1.2899x over previous
//
#include <hip/hip_runtime.h>
#include <math.h>

// Problem constants
#define BB 4
#define CC 64
#define HH 64
#define WW 4096
#define TW 128
#define THREADS 512            // 8 waves/block
#define NT (WW / TW)            // 32 tiles along W
#define CH_STRIDE ((size_t)HH * WW)   // 262144

#if __has_builtin(__builtin_amdgcn_rcpf)
__device__ __forceinline__ float fast_rcp(float v) { return __builtin_amdgcn_rcpf(v); }
#else
__device__ __forceinline__ float fast_rcp(float v) { return 1.0f / v; }
#endif

// ---------------------------------------------------------------------------
// Prep kernel: reshuffle weights into vector-load-friendly layouts in d_ws.
// WA[gc][c][k][tap][fg]  : 16 * 32 * 16 = 8192 floats   (conv weights)
//   gc 0..7  -> left conv (wl), rows jr = (gc&7)*4 + k, f=row jr, g=row jr+32
//   gc 8..15 -> right conv (wr)
// WB[gc][c][j]           : 16 * 64 * 8 = 8192 floats    (pointwise weights)
//   gc 0..7  -> w_skp rows (gc&7)*8 + j ; gc 8..15 -> w_hid rows
// WA and WB are contiguous (16384 floats) so the main kernel stages both
// with one cooperative copy.
// ---------------------------------------------------------------------------
__global__ void prep_weights(const float* __restrict__ wl, const float* __restrict__ wr,
                             const float* __restrict__ w_skp, const float* __restrict__ w_hid,
                             float* __restrict__ WA, float* __restrict__ WB) {
    int i = blockIdx.x * blockDim.x + threadIdx.x;
    if (i < 8192) {
        // WA decode: i = (((gc*32 + c)*4 + k)*2 + tap)*2 + fg
        int fg  = i & 1;
        int tap = (i >> 1) & 1;
        int k   = (i >> 2) & 3;
        int c   = (i >> 4) & 31;
        int gc  = i >> 9;
        int half = gc >> 3;
        int jr   = (gc & 7) * 4 + k;
        const float* wsrc = half ? wr : wl;     // [64][32][1][2] flat: o*64 + c*2 + t
        int o = jr + (fg ? 32 : 0);
        WA[i] = wsrc[o * 64 + c * 2 + tap];

        // WB decode: i = (gc*64 + c)*8 + j
        int j  = i & 7;
        int c2 = (i >> 3) & 63;
        int g2 = i >> 9;
        int is_hid = g2 >> 3;
        int r = (g2 & 7) * 8 + j;
        const float* psrc = is_hid ? w_hid : w_skp;  // [64][64] flat: o*64 + c
        WB[i] = psrc[r * 64 + c2];
    }
}

// ---------------------------------------------------------------------------
// Fused residual-block kernel.
// Block = one (b, h, w-tile). 512 threads = 8 waves; each wave owns 2 gc.
// Lane -> 2 consecutive w positions (w0 = lane*2).
//
// History:
//  R4  SMEM weights, 2 waves/SIMD:      1102us, VALUBusy 26%
//  R7  VMEM weights, 2 waves/SIMD:      1122us, VALUBusy 31%
//  R8  VMEM weights, 4 waves/SIMD:      1115us, VALUBusy 31.4%  <- occupancy
//      doubled, duration identical => NOT TLP-limited. Weight loads miss
//      L1/K$ every block (64KB footprint + 34KB Xs stream evicts), ~200cy
//      L2 misses bounded by per-CU MSHRs, shared by all waves.
//  R9: stage ALL weights (64KB) into LDS once per block; hot-loop weight
//      reads become same-address ds_read_b128 broadcasts (conflict-free,
//      in-order). LDS 130KB -> 1 block/CU (occupancy proven irrelevant).
// ---------------------------------------------------------------------------
__global__ __launch_bounds__(THREADS, 1)
void resblock_kernel(const float* __restrict__ x,
                     const float* __restrict__ Wg,   // WA(8192) ++ WB(8192) in d_ws
                     const float* __restrict__ bl, const float* __restrict__ br,
                     const float* __restrict__ b_skp, const float* __restrict__ b_hid,
                     float* __restrict__ out1, float* __restrict__ out2) {
    __shared__ float Xs[CC][TW + 8];   // 34.0 KB: 0..3 halo, 4..131 body, 132..135 halo
    __shared__ float Hs[CC][TW];       // 32 KB: gated activations
    __shared__ float Ws[16384];        // 64 KB: WA ++ WB

    const int tid = threadIdx.x;
    const int bid = blockIdx.x;
    const int wt = bid & (NT - 1);
    const int h  = (bid >> 5) & (HH - 1);
    const int b  = bid >> 11;
    const int w_base = wt * TW;

    const float* xrow = x + ((size_t)b * CC) * CH_STRIDE + (size_t)h * WW; // x[b][0][h][0]

    // ---- stage weights into LDS (once per block) ----
    // 16384 floats = 4096 float4; 512 threads x 8 float4 each, coalesced.
    for (int i = tid; i < 4096; i += THREADS) {
        reinterpret_cast<float4*>(Ws)[i] = reinterpret_cast<const float4*>(Wg)[i];
    }

    // ---- load x tile into LDS ----
    // body: 64 rows x 32 float4 (aligned, fully in-bounds)
    for (int i = tid; i < CC * 32; i += THREADS) {
        int row = i >> 5, c4 = i & 31;
        float4 v = *reinterpret_cast<const float4*>(xrow + (size_t)row * CH_STRIDE + w_base + c4 * 4);
        *reinterpret_cast<float4*>(&Xs[row][4 + c4 * 4]) = v;
    }
    // halos: 64 rows x 8 scalars, zero-padded at edges
    for (int i = tid; i < CC * 8; i += THREADS) {
        int row = i >> 3, k = i & 7;
        int col = (k < 4) ? k : (TW + k);          // 0..3 or 132..135
        int gw = w_base + col - 4;
        float v = 0.0f;
        if (gw >= 0 && gw < WW) v = xrow[(size_t)row * CH_STRIDE + gw];
        Xs[row][col] = v;
    }
    __syncthreads();

    const int wave = __builtin_amdgcn_readfirstlane(tid >> 6);   // 0..7
    const int lane = tid & 63;
    const int w0 = lane * 2;                       // tile-local position

    // ---- Stage A: dilated convs + gated activation -> Hs ----
    // wave handles gc = wave*2 + it (it = 0,1); each gc = 4 (f,g) pairs x 2 w.
    for (int it = 0; it < 2; ++it) {
        int gc = wave * 2 + it;
        int half = gc >> 3;                        // 0: left conv, 1: right conv (uniform per wave)
        int jr0 = (gc & 7) * 4;
        const float4* wa4 = reinterpret_cast<const float4*>(&Ws[gc * 512]); // LDS broadcast
        int xr0 = half * 32;                       // input channel base
        int xbase = w0 + (half ? 4 : 0);           // tap-0 LDS col for this lane
        const float* bsrc = half ? br : bl;

        float accf[4][2], accg[4][2];
        #pragma unroll
        for (int k = 0; k < 4; ++k) {
            float bf = bsrc[jr0 + k];
            float bg = bsrc[jr0 + k + 32];
            accf[k][0] = bf; accf[k][1] = bf;
            accg[k][0] = bg; accg[k][1] = bg;
        }

        #pragma unroll 8
        for (int c = 0; c < 32; ++c) {
            float x0 = Xs[xr0 + c][xbase];         // tap0 @ w0
            float x1 = Xs[xr0 + c][xbase + 1];     // tap0 @ w0+1
            float x2 = Xs[xr0 + c][xbase + 4];     // tap1 @ w0
            float x3 = Xs[xr0 + c][xbase + 5];     // tap1 @ w0+1
            float4 wk[4];                          // wk[k] = (t0f, t0g, t1f, t1g)
            wk[0] = wa4[c * 4 + 0];
            wk[1] = wa4[c * 4 + 1];
            wk[2] = wa4[c * 4 + 2];
            wk[3] = wa4[c * 4 + 3];
            #pragma unroll
            for (int k = 0; k < 4; ++k) {
                accf[k][0] += wk[k].x * x0; accf[k][0] += wk[k].z * x2;
                accf[k][1] += wk[k].x * x1; accf[k][1] += wk[k].z * x3;
                accg[k][0] += wk[k].y * x0; accg[k][0] += wk[k].w * x2;
                accg[k][1] += wk[k].y * x1; accg[k][1] += wk[k].w * x3;
            }
        }

        // activation: h = tanh(f) * sigmoid(g)
        #pragma unroll
        for (int k = 0; k < 4; ++k) {
            int ch = half * 32 + jr0 + k;
            #pragma unroll
            for (int n = 0; n < 2; ++n) {
                float f = accf[k][n], g = accg[k][n];
                float th = 1.0f - 2.0f * fast_rcp(1.0f + __expf(2.0f * f));
                float sg = fast_rcp(1.0f + __expf(-g));
                Hs[ch][w0 + n] = th * sg;
            }
        }
    }
    __syncthreads();

    // ---- Stage B: two 64x64 pointwise matmuls + bias + residual ----
    for (int it = 0; it < 2; ++it) {
        int gc = wave * 2 + it;
        int is_hid = gc >> 3;                      // uniform per wave
        int r0 = (gc & 7) * 8;
        const float4* wb4 = reinterpret_cast<const float4*>(&Ws[8192 + gc * 512]); // LDS broadcast
        const float* bsrc = is_hid ? b_hid : b_skp;

        float acc[8][2];
        #pragma unroll
        for (int j = 0; j < 8; ++j) {
            float bv = bsrc[r0 + j];
            acc[j][0] = bv; acc[j][1] = bv;
        }

        #pragma unroll 8
        for (int c = 0; c < 64; ++c) {
            float h0 = Hs[c][w0];
            float h1 = Hs[c][w0 + 1];
            float4 wlo = wb4[c * 2 + 0];           // weights j=0..3
            float4 whi = wb4[c * 2 + 1];           // weights j=4..7
            acc[0][0] += wlo.x * h0; acc[0][1] += wlo.x * h1;
            acc[1][0] += wlo.y * h0; acc[1][1] += wlo.y * h1;
            acc[2][0] += wlo.z * h0; acc[2][1] += wlo.z * h1;
            acc[3][0] += wlo.w * h0; acc[3][1] += wlo.w * h1;
            acc[4][0] += whi.x * h0; acc[4][1] += whi.x * h1;
            acc[5][0] += whi.y * h0; acc[5][1] += whi.y * h1;
            acc[6][0] += whi.z * h0; acc[6][1] += whi.z * h1;
            acc[7][0] += whi.w * h0; acc[7][1] += whi.w * h1;
        }

        float* outp = is_hid ? out1 : out2;
        #pragma unroll
        for (int j = 0; j < 8; ++j) {
            int ch = r0 + j;
            float v0 = acc[j][0], v1 = acc[j][1];
            if (is_hid) {                          // residual: x + hid
                v0 += Xs[ch][w0 + 4];
                v1 += Xs[ch][w0 + 5];
            }
            size_t oidx = (((size_t)b * CC + ch) * HH + h) * WW + w_base + w0;
            float2 vv = make_float2(v0, v1);
            *reinterpret_cast<float2*>(outp + oidx) = vv;
        }
    }
}

// ---------------------------------------------------------------------------
extern "C" void kernel_launch(void* const* d_in, const int* in_sizes, int n_in,
                              void* d_out, int out_size, void* d_ws, size_t ws_size,
                              hipStream_t stream) {
    const float* x     = (const float*)d_in[0];
    const float* wl    = (const float*)d_in[1];
    const float* bl    = (const float*)d_in[2];
    const float* wr    = (const float*)d_in[3];
    const float* br    = (const float*)d_in[4];
    const float* w_skp = (const float*)d_in[5];
    const float* b_skp = (const float*)d_in[6];
    const float* w_hid = (const float*)d_in[7];
    const float* b_hid = (const float*)d_in[8];

    float* WA = (float*)d_ws;          // 8192 floats
    float* WB = WA + 8192;             // 8192 floats (total 64 KB of d_ws, contiguous)

    float* out1 = (float*)d_out;                           // x + hid
    float* out2 = out1 + (size_t)BB * CC * HH * WW;        // o (skip)

    prep_weights<<<32, 256, 0, stream>>>(wl, wr, w_skp, w_hid, WA, WB);

    int grid = BB * HH * NT;   // 4*64*32 = 8192
    resblock_kernel<<<grid, THREADS, 0, stream>>>(x, WA, bl, br, b_skp, b_hid, out1, out2);
}